// Round 1
// baseline (256.354 us; speedup 1.0000x reference)
//
#include <hip/hip_runtime.h>
#include <stdint.h>

typedef unsigned int  u32;
typedef unsigned short u16;
typedef __bf16 bf16x8 __attribute__((ext_vector_type(8)));
typedef float  f32x4  __attribute__((ext_vector_type(4)));

// db4 correlation filters (pywt dec_lo/dec_hi reversed), matching lax.conv
__constant__ float GL[8] = { 0.23037781330885523f,  0.7148465705525415f,
                             0.6308807679295904f,  -0.02798376941698385f,
                            -0.18703481171888114f,  0.030841381835986965f,
                             0.032883011666982945f,-0.010597401784997278f };
__constant__ float GH[8] = {-0.010597401784997278f,-0.032883011666982945f,
                             0.030841381835986965f, 0.18703481171888114f,
                            -0.02798376941698385f, -0.6308807679295904f,
                             0.7148465705525415f,  -0.23037781330885523f };

// ---------------------------------------------------------------------------
// Kernel 1: build the 84x64 DWT analysis matrix by transforming basis vectors.
// Wd[t*64 + tau]; coeff order: lo3 (14) | hi1 (35) | hi2 (21) | hi3 (14)
// ---------------------------------------------------------------------------
__global__ void build_wdwt(float* __restrict__ Wd) {
    const int j = threadIdx.x;  // basis index 0..63
    float lo1[35], lo2[21];
    // level 1: N=64, pad p=12 (even) -> reflect 6 each side, out 35
#pragma unroll
    for (int i = 0; i < 35; ++i) {
        float sl = 0.f, sh = 0.f;
#pragma unroll
        for (int t = 0; t < 8; ++t) {
            int s = 2 * i + t - 6;
            if (s < 0) s = -s;
            if (s >= 64) s = 126 - s;
            float xv = (s == j) ? 1.0f : 0.0f;
            sl += xv * GL[t]; sh += xv * GH[t];
        }
        lo1[i] = sl;
        Wd[(14 + i) * 64 + j] = sh;
    }
    // level 2: N=35, p=13 odd -> one zero appended (len 36), reflect 6, out 21
#pragma unroll
    for (int i = 0; i < 21; ++i) {
        float sl = 0.f, sh = 0.f;
#pragma unroll
        for (int t = 0; t < 8; ++t) {
            int s = 2 * i + t - 6;
            if (s < 0) s = -s;
            if (s >= 36) s = 70 - s;
            float xv = (s >= 35) ? 0.0f : lo1[s];
            sl += xv * GL[t]; sh += xv * GH[t];
        }
        lo2[i] = sl;
        Wd[(49 + i) * 64 + j] = sh;
    }
    // level 3: N=21, p=13 odd -> zero appended (len 22), reflect 6, out 14
#pragma unroll
    for (int i = 0; i < 14; ++i) {
        float sl = 0.f, sh = 0.f;
#pragma unroll
        for (int t = 0; t < 8; ++t) {
            int s = 2 * i + t - 6;
            if (s < 0) s = -s;
            if (s >= 22) s = 42 - s;
            float xv = (s >= 21) ? 0.0f : lo2[s];
            sl += xv * GL[t]; sh += xv * GH[t];
        }
        Wd[i * 64 + j] = sl;
        Wd[(70 + i) * 64 + j] = sh;
    }
}

// ---------------------------------------------------------------------------
// fp32 -> bf16 RNE helpers
// ---------------------------------------------------------------------------
__device__ inline u16 f32_bf16(float f) {
    u32 u = __float_as_uint(f);
    u += 0x7fffu + ((u >> 16) & 1u);
    return (u16)(u >> 16);
}
__device__ inline u32 pack2_bf16(float a, float b) {
    u32 ua = __float_as_uint(a); ua += 0x7fffu + ((ua >> 16) & 1u);
    u32 ub = __float_as_uint(b); ub += 0x7fffu + ((ub >> 16) & 1u);
    return (ua >> 16) | (ub & 0xffff0000u);
}

// ---------------------------------------------------------------------------
// Kernel 2: fold DWT into conv weights.
// Wp[sk][tau*64 + hw] = sum_t cw[sk][t*64+hw] * Wd[t*64+tau], stored bf16.
// One block per (s,k). hw = lane (coalesced), tau group uniform per wave so
// Wd reads become scalar loads.
// ---------------------------------------------------------------------------
__global__ __launch_bounds__(256) void fold_w(const float* __restrict__ cw,
                                              const float* __restrict__ Wd,
                                              u16* __restrict__ Wp) {
    const int sk = blockIdx.x;                    // 0..511
    const int hw = threadIdx.x & 63;
    const int tg = __builtin_amdgcn_readfirstlane((int)(threadIdx.x >> 6)); // 0..3
    const int t0 = tg * 16;
    const float* wk = cw + (size_t)sk * (84 * 64);
    float acc[16];
#pragma unroll
    for (int j = 0; j < 16; ++j) acc[j] = 0.f;
#pragma unroll 4
    for (int t = 0; t < 84; ++t) {
        float wv = wk[t * 64 + hw];
        const float* Wr = Wd + t * 64 + t0;
#pragma unroll
        for (int j = 0; j < 16; ++j) acc[j] += wv * Wr[j];
    }
    u16* dst = Wp + (size_t)sk * 4096 + hw;
#pragma unroll
    for (int j = 0; j < 16; ++j) dst[(t0 + j) * 64] = f32_bf16(acc[j]);
}

// ---------------------------------------------------------------------------
// Kernel 3: C[b, s*128+n] = leaky_relu( X[b, s*4096+i] . Wp[s*128+n][i] + bias )
// BM=BN=BK=64, 256 threads (4 waves in 2x2), wave computes 32x32.
// LDS bf16 tiles, XOR swizzle: chunk(16B) c of row r stored at c ^ (r&7).
// X is fp32 in global; converted to bf16 (RNE) during staging.
// ---------------------------------------------------------------------------
__global__ __launch_bounds__(256) void gemm_dwt(const float* __restrict__ X,
                                                const u16* __restrict__ Wp,
                                                const float* __restrict__ bias,
                                                float* __restrict__ out) {
    const int nh = blockIdx.x;   // n-half: 0,1
    const int mt = blockIdx.y;   // m-tile: 0..31
    const int s  = blockIdx.z;   // subwindow 0..3
    const int tid  = threadIdx.x;
    const int lane = tid & 63;
    const int wv   = tid >> 6;           // wave 0..3
    const int wm   = wv & 1;             // wave m (0/1)
    const int wn   = wv >> 1;            // wave n (0/1)
    const int fr   = lane & 15;          // fragment row/col in 16x16 tile
    const int fq   = lane >> 4;          // quad 0..3

    __shared__ __align__(16) u16 Xl[64 * 64];
    __shared__ __align__(16) u16 Wl[64 * 64];

    // staging: thread -> (row, 2 consecutive 16B chunks)
    const int srow = tid >> 2;           // 0..63
    const int sc2  = (tid & 3) * 2;      // chunk base 0,2,4,6 (of 8 per row)
    const float* xg = X + (size_t)(mt * 64 + srow) * 16384 + s * 4096 + sc2 * 8;
    const u16*   wg = Wp + (size_t)(s * 128 + nh * 64 + srow) * 4096 + sc2 * 8;
    const int xw0 = srow * 64 + (((sc2    ) ^ (srow & 7)) << 3); // ushort idx
    const int xw1 = srow * 64 + (((sc2 + 1) ^ (srow & 7)) << 3);

    // fragment read row bases (swizzle key is fr&7 for all of them)
    const int ar0 = (wm * 32 + fr) * 64;
    const int ar1 = ar0 + 16 * 64;
    const int br0 = (wn * 32 + fr) * 64;
    const int br1 = br0 + 16 * 64;
    const int sk7 = fr & 7;

    f32x4 acc00 = {0.f, 0.f, 0.f, 0.f}, acc01 = acc00, acc10 = acc00, acc11 = acc00;

    // prologue: load kt=0 into registers
    float4 xa, xb, xc, xd; uint4 wa, wb;
    {
        const float4* xp = reinterpret_cast<const float4*>(xg);
        xa = xp[0]; xb = xp[1]; xc = xp[2]; xd = xp[3];
        const uint4* wp4 = reinterpret_cast<const uint4*>(wg);
        wa = wp4[0]; wb = wp4[1];
    }

    for (int kt = 0; kt < 64; ++kt) {
        __syncthreads();   // previous compute done reading LDS
        // store staged tile (fp32 -> bf16 pack for X)
        {
            uint4 pa, pb;
            pa.x = pack2_bf16(xa.x, xa.y); pa.y = pack2_bf16(xa.z, xa.w);
            pa.z = pack2_bf16(xb.x, xb.y); pa.w = pack2_bf16(xb.z, xb.w);
            pb.x = pack2_bf16(xc.x, xc.y); pb.y = pack2_bf16(xc.z, xc.w);
            pb.z = pack2_bf16(xd.x, xd.y); pb.w = pack2_bf16(xd.z, xd.w);
            *reinterpret_cast<uint4*>(&Xl[xw0]) = pa;
            *reinterpret_cast<uint4*>(&Xl[xw1]) = pb;
            *reinterpret_cast<uint4*>(&Wl[xw0]) = wa;
            *reinterpret_cast<uint4*>(&Wl[xw1]) = wb;
        }
        __syncthreads();
        // prefetch next k-tile (consumed next iteration)
        {
            const int kn = (kt + 1 < 64) ? kt + 1 : 63;
            const float4* xp = reinterpret_cast<const float4*>(xg + (size_t)kn * 64);
            xa = xp[0]; xb = xp[1]; xc = xp[2]; xd = xp[3];
            const uint4* wp4 = reinterpret_cast<const uint4*>(wg + (size_t)kn * 64);
            wa = wp4[0]; wb = wp4[1];
        }
        // compute on current LDS tile
#pragma unroll
        for (int h = 0; h < 2; ++h) {
            const int q = h * 4 + fq;
            const int co = ((q ^ sk7) << 3);
            bf16x8 a0 = *reinterpret_cast<const bf16x8*>(&Xl[ar0 + co]);
            bf16x8 a1 = *reinterpret_cast<const bf16x8*>(&Xl[ar1 + co]);
            bf16x8 b0 = *reinterpret_cast<const bf16x8*>(&Wl[br0 + co]);
            bf16x8 b1 = *reinterpret_cast<const bf16x8*>(&Wl[br1 + co]);
            acc00 = __builtin_amdgcn_mfma_f32_16x16x32_bf16(a0, b0, acc00, 0, 0, 0);
            acc01 = __builtin_amdgcn_mfma_f32_16x16x32_bf16(a0, b1, acc01, 0, 0, 0);
            acc10 = __builtin_amdgcn_mfma_f32_16x16x32_bf16(a1, b0, acc10, 0, 0, 0);
            acc11 = __builtin_amdgcn_mfma_f32_16x16x32_bf16(a1, b1, acc11, 0, 0, 0);
        }
    }

    // epilogue: D[row = quad*4+r][col = lane&15] per 16x16 tile
    const float* bb = bias + s * 128 + nh * 64 + wn * 32;
    float* og = out + (size_t)(mt * 64 + wm * 32) * 512 + s * 128 + nh * 64 + wn * 32;
    const float b0v = bb[fr], b1v = bb[16 + fr];
#pragma unroll
    for (int r = 0; r < 4; ++r) {
        const int row0 = fq * 4 + r;
        float v;
        v = acc00[r] + b0v; og[(size_t)(row0     ) * 512 + fr     ] = v > 0.f ? v : 0.01f * v;
        v = acc01[r] + b1v; og[(size_t)(row0     ) * 512 + 16 + fr] = v > 0.f ? v : 0.01f * v;
        v = acc10[r] + b0v; og[(size_t)(row0 + 16) * 512 + fr     ] = v > 0.f ? v : 0.01f * v;
        v = acc11[r] + b1v; og[(size_t)(row0 + 16) * 512 + 16 + fr] = v > 0.f ? v : 0.01f * v;
    }
}

// ---------------------------------------------------------------------------
extern "C" void kernel_launch(void* const* d_in, const int* in_sizes, int n_in,
                              void* d_out, int out_size, void* d_ws, size_t ws_size,
                              hipStream_t stream) {
    const float* x  = (const float*)d_in[0];   // [2048,1,256,8,8] fp32
    const float* cw = (const float*)d_in[1];   // [4,128,84,8,8]   fp32
    const float* cb = (const float*)d_in[2];   // [4,128]          fp32
    float* out = (float*)d_out;                // [2048,512]       fp32

    float* Wd = (float*)d_ws;                        // 84*64 fp32 = 21504 B
    u16*   Wp = (u16*)((char*)d_ws + 32768);         // 512*4096 bf16 = 4 MiB

    build_wdwt<<<1, 64, 0, stream>>>(Wd);
    fold_w<<<512, 256, 0, stream>>>(cw, Wd, Wp);
    gemm_dwt<<<dim3(2, 32, 4), 256, 0, stream>>>(x, Wp, cb, out);
}

// Round 2
// 251.662 us; speedup vs baseline: 1.0186x; 1.0186x over previous
//
#include <hip/hip_runtime.h>
#include <stdint.h>

typedef unsigned int  u32;
typedef unsigned short u16;
typedef __bf16 bf16x8 __attribute__((ext_vector_type(8)));
typedef float  f32x4  __attribute__((ext_vector_type(4)));

// db4 correlation filters (pywt dec_lo/dec_hi reversed), matching lax.conv
__constant__ float GL[8] = { 0.23037781330885523f,  0.7148465705525415f,
                             0.6308807679295904f,  -0.02798376941698385f,
                            -0.18703481171888114f,  0.030841381835986965f,
                             0.032883011666982945f,-0.010597401784997278f };
__constant__ float GH[8] = {-0.010597401784997278f,-0.032883011666982945f,
                             0.030841381835986965f, 0.18703481171888114f,
                            -0.02798376941698385f, -0.6308807679295904f,
                             0.7148465705525415f,  -0.23037781330885523f };

// ---------------------------------------------------------------------------
// fp32 -> bf16 RNE helpers
// ---------------------------------------------------------------------------
__device__ inline u16 f32_bf16(float f) {
    u32 u = __float_as_uint(f);
    u += 0x7fffu + ((u >> 16) & 1u);
    return (u16)(u >> 16);
}
__device__ inline u32 pack2_bf16(float a, float b) {
    u32 ua = __float_as_uint(a); ua += 0x7fffu + ((ua >> 16) & 1u);
    u32 ub = __float_as_uint(b); ub += 0x7fffu + ((ub >> 16) & 1u);
    return (ua >> 16) | (ub & 0xffff0000u);
}

// ---------------------------------------------------------------------------
// Kernel 1 (merged): build 84x64 DWT matrix in LDS (wave 0), then fold it
// into the conv weights:  Wp[sk][tau*64 + hw] = sum_t cw[sk][t*64+hw]*Wd[t][tau]
// One block per (s,k); hw = lane (coalesced); tau group uniform per wave.
// Wd coeff order: lo3 (14) | hi1 (35) | hi2 (21) | hi3 (14)
// ---------------------------------------------------------------------------
__global__ __launch_bounds__(256) void fold_w(const float* __restrict__ cw,
                                              u16* __restrict__ Wp) {
    __shared__ float WdL[84 * 64];
    const int tid = threadIdx.x;

    if (tid < 64) {   // wave 0 builds the DWT analysis matrix
        const int j = tid;           // basis index 0..63
        float lo1[35], lo2[21];
        // level 1: N=64, pad p=12 even -> reflect 6 each side, out 35
#pragma unroll
        for (int i = 0; i < 35; ++i) {
            float sl = 0.f, sh = 0.f;
#pragma unroll
            for (int t = 0; t < 8; ++t) {
                int s = 2 * i + t - 6;
                if (s < 0) s = -s;
                if (s >= 64) s = 126 - s;
                float xv = (s == j) ? 1.0f : 0.0f;
                sl += xv * GL[t]; sh += xv * GH[t];
            }
            lo1[i] = sl;
            WdL[(14 + i) * 64 + j] = sh;
        }
        // level 2: N=35, p=13 odd -> zero appended (len 36), reflect 6, out 21
#pragma unroll
        for (int i = 0; i < 21; ++i) {
            float sl = 0.f, sh = 0.f;
#pragma unroll
            for (int t = 0; t < 8; ++t) {
                int s = 2 * i + t - 6;
                if (s < 0) s = -s;
                if (s >= 36) s = 70 - s;
                float xv = (s >= 35) ? 0.0f : lo1[s];
                sl += xv * GL[t]; sh += xv * GH[t];
            }
            lo2[i] = sl;
            WdL[(49 + i) * 64 + j] = sh;
        }
        // level 3: N=21, p=13 odd -> zero appended (len 22), reflect 6, out 14
#pragma unroll
        for (int i = 0; i < 14; ++i) {
            float sl = 0.f, sh = 0.f;
#pragma unroll
            for (int t = 0; t < 8; ++t) {
                int s = 2 * i + t - 6;
                if (s < 0) s = -s;
                if (s >= 22) s = 42 - s;
                float xv = (s >= 21) ? 0.0f : lo2[s];
                sl += xv * GL[t]; sh += xv * GH[t];
            }
            WdL[i * 64 + j] = sl;
            WdL[(70 + i) * 64 + j] = sh;
        }
    }
    __syncthreads();

    const int sk = blockIdx.x;                    // 0..511
    const int hw = tid & 63;
    const int tg = __builtin_amdgcn_readfirstlane((int)(tid >> 6)); // 0..3
    const int t0 = tg * 16;
    const float* wk = cw + (size_t)sk * (84 * 64);
    float acc[16];
#pragma unroll
    for (int j = 0; j < 16; ++j) acc[j] = 0.f;
#pragma unroll 4
    for (int t = 0; t < 84; ++t) {
        float wv = wk[t * 64 + hw];
        const float* Wr = WdL + t * 64 + t0;
#pragma unroll
        for (int j = 0; j < 16; ++j) acc[j] += wv * Wr[j];
    }
    u16* dst = Wp + (size_t)sk * 4096 + hw;
#pragma unroll
    for (int j = 0; j < 16; ++j) dst[(t0 + j) * 64] = f32_bf16(acc[j]);
}

// ---------------------------------------------------------------------------
// Kernel 2: C[b, s*128+n] = leaky_relu( X[b, s*4096+i] . Wp[s*128+n][i] + b )
// BM=16, BN=64, BK=64; 256 threads = 4 waves, each wave a 16x16 output tile.
// Grid (nh=2, mt=128, s=4) = 1024 blocks -> 4 blocks/CU, 16 waves/CU.
// LDS bf16 tiles, XOR swizzle: 16B chunk c of row r stored at c ^ (r&7).
// X fp32 in global, converted to bf16 RNE during staging.
// ---------------------------------------------------------------------------
__global__ __launch_bounds__(256) void gemm_dwt(const float* __restrict__ X,
                                                const u16* __restrict__ Wp,
                                                const float* __restrict__ bias,
                                                float* __restrict__ out) {
    const int nh = blockIdx.x;   // n-half of this s: 0,1
    const int mt = blockIdx.y;   // m-tile: 0..127 (16 rows each)
    const int s  = blockIdx.z;   // subwindow 0..3
    const int tid  = threadIdx.x;
    const int lane = tid & 63;
    const int w    = tid >> 6;           // wave 0..3 -> n-subtile
    const int fr   = lane & 15;
    const int fq   = (lane >> 4) & 3;

    __shared__ __align__(16) u16 Xl[16 * 64];
    __shared__ __align__(16) u16 Wl[64 * 64];

    // W staging: 64 rows x 8 chunks(16B) = 512 chunks, 2 per thread
    const int wrow = tid >> 2;           // 0..63
    const int wc2  = (tid & 3) * 2;      // chunk base 0,2,4,6
    const u16* wg = Wp + (size_t)(s * 128 + nh * 64 + wrow) * 4096 + wc2 * 8;
    const int ww0 = wrow * 64 + (((wc2    ) ^ (wrow & 7)) << 3);
    const int ww1 = wrow * 64 + (((wc2 + 1) ^ (wrow & 7)) << 3);

    // X staging: 16 rows x 8 chunks = 128 chunks, threads 0..127, 1 each
    const bool doX = tid < 128;
    const int xrow = (tid >> 3) & 15;    // 0..15
    const int xch  = tid & 7;            // 0..7
    const float* xg = X + (size_t)(mt * 16 + xrow) * 16384 + s * 4096 + xch * 8;
    const int xw = xrow * 64 + ((xch ^ (xrow & 7)) << 3);

    const int sk7 = fr & 7;
    const int ar  = fr * 64;                 // a-frag row base
    const int br  = (w * 16 + fr) * 64;      // b-frag row base

    f32x4 acc = {0.f, 0.f, 0.f, 0.f};

    // prologue: k-tile 0 into registers
    float4 xa, xb; uint4 wa, wb;
    {
        const uint4* wp4 = reinterpret_cast<const uint4*>(wg);
        wa = wp4[0]; wb = wp4[1];
        if (doX) {
            const float4* xp = reinterpret_cast<const float4*>(xg);
            xa = xp[0]; xb = xp[1];
        }
    }

    for (int kt = 0; kt < 64; ++kt) {
        __syncthreads();   // previous compute done reading LDS
        if (doX) {
            uint4 p;
            p.x = pack2_bf16(xa.x, xa.y); p.y = pack2_bf16(xa.z, xa.w);
            p.z = pack2_bf16(xb.x, xb.y); p.w = pack2_bf16(xb.z, xb.w);
            *reinterpret_cast<uint4*>(&Xl[xw]) = p;
        }
        *reinterpret_cast<uint4*>(&Wl[ww0]) = wa;
        *reinterpret_cast<uint4*>(&Wl[ww1]) = wb;
        __syncthreads();
        // prefetch next k-tile
        {
            const int kn = (kt + 1 < 64) ? kt + 1 : 63;
            const uint4* wp4 = reinterpret_cast<const uint4*>(wg + (size_t)kn * 64);
            wa = wp4[0]; wb = wp4[1];
            if (doX) {
                const float4* xp = reinterpret_cast<const float4*>(xg + (size_t)kn * 64);
                xa = xp[0]; xb = xp[1];
            }
        }
        // compute on current tile
#pragma unroll
        for (int h = 0; h < 2; ++h) {
            const int q  = h * 4 + fq;
            const int co = ((q ^ sk7) << 3);
            bf16x8 a = *reinterpret_cast<const bf16x8*>(&Xl[ar + co]);
            bf16x8 b = *reinterpret_cast<const bf16x8*>(&Wl[br + co]);
            acc = __builtin_amdgcn_mfma_f32_16x16x32_bf16(a, b, acc, 0, 0, 0);
        }
    }

    // epilogue: D[row = fq*4+r][col = fr] ; col_global = s*128+nh*64+w*16+fr
    const int colg = s * 128 + nh * 64 + w * 16 + fr;
    const float bv = bias[colg];
    float* og = out + (size_t)(mt * 16) * 512 + colg;
#pragma unroll
    for (int r = 0; r < 4; ++r) {
        const int row = fq * 4 + r;
        float v = acc[r] + bv;
        og[(size_t)row * 512] = v > 0.f ? v : 0.01f * v;
    }
}

// ---------------------------------------------------------------------------
extern "C" void kernel_launch(void* const* d_in, const int* in_sizes, int n_in,
                              void* d_out, int out_size, void* d_ws, size_t ws_size,
                              hipStream_t stream) {
    const float* x  = (const float*)d_in[0];   // [2048,1,256,8,8] fp32
    const float* cw = (const float*)d_in[1];   // [4,128,84,8,8]   fp32
    const float* cb = (const float*)d_in[2];   // [4,128]          fp32
    float* out = (float*)d_out;                // [2048,512]       fp32

    u16* Wp = (u16*)d_ws;                      // 512*4096 bf16 = 4 MiB

    fold_w<<<512, 256, 0, stream>>>(cw, Wp);
    gemm_dwt<<<dim3(2, 128, 4), 256, 0, stream>>>(x, Wp, cb, out);
}

// Round 4
// 246.064 us; speedup vs baseline: 1.0418x; 1.0227x over previous
//
#include <hip/hip_runtime.h>
#include <stdint.h>

typedef unsigned int  u32;
typedef unsigned short u16;
typedef __bf16 bf16x8 __attribute__((ext_vector_type(8)));
typedef float  f32x4  __attribute__((ext_vector_type(4)));
typedef u32    u32x4  __attribute__((ext_vector_type(4)));

// db4 correlation filters (pywt dec_lo/dec_hi reversed), matching lax.conv
__constant__ float GL[8] = { 0.23037781330885523f,  0.7148465705525415f,
                             0.6308807679295904f,  -0.02798376941698385f,
                            -0.18703481171888114f,  0.030841381835986965f,
                             0.032883011666982945f,-0.010597401784997278f };
__constant__ float GH[8] = {-0.010597401784997278f,-0.032883011666982945f,
                             0.030841381835986965f, 0.18703481171888114f,
                            -0.02798376941698385f, -0.6308807679295904f,
                             0.7148465705525415f,  -0.23037781330885523f };

__device__ inline u16 f32_bf16(float f) {
    u32 u = __float_as_uint(f);
    u += 0x7fffu + ((u >> 16) & 1u);
    return (u16)(u >> 16);
}
__device__ inline u32 pack2_bf16(float a, float b) {
    u32 ua = __float_as_uint(a); ua += 0x7fffu + ((ua >> 16) & 1u);
    u32 ub = __float_as_uint(b); ub += 0x7fffu + ((ub >> 16) & 1u);
    return (ua >> 16) | (ub & 0xffff0000u);
}

// ---------------------------------------------------------------------------
// Kernel 1: build 84x64 DWT matrix in LDS (wave 0), then fold into conv
// weights, emitting bf16 directly in MFMA B-fragment order:
//   Wf[(((s*8+nt)*128 + kb)*64 + lane)*8 + j]
//     = Wp[n = nt*16 + (lane&15)][i = kb*32 + (lane>>4)*8 + j]
// where Wp[n][i = t*64 + hw] = sum_tau cw[s,n,tau,hw] * Wd[tau][t].
// One block per (s,n). Wd order: lo3(14) | hi1(35) | hi2(21) | hi3(14).
// ---------------------------------------------------------------------------
__global__ __launch_bounds__(256) void fold_w(const float* __restrict__ cw,
                                              u16* __restrict__ Wf) {
    __shared__ float WdL[84 * 64];
    const int tid = threadIdx.x;

    if (tid < 64) {   // wave 0 builds the DWT analysis matrix
        const int j = tid;           // basis index 0..63
        float lo1[35], lo2[21];
#pragma unroll
        for (int i = 0; i < 35; ++i) {            // level 1: N=64, reflect 6
            float sl = 0.f, sh = 0.f;
#pragma unroll
            for (int t = 0; t < 8; ++t) {
                int s = 2 * i + t - 6;
                if (s < 0) s = -s;
                if (s >= 64) s = 126 - s;
                float xv = (s == j) ? 1.0f : 0.0f;
                sl += xv * GL[t]; sh += xv * GH[t];
            }
            lo1[i] = sl;
            WdL[(14 + i) * 64 + j] = sh;
        }
#pragma unroll
        for (int i = 0; i < 21; ++i) {            // level 2: N=35 (+1 zero)
            float sl = 0.f, sh = 0.f;
#pragma unroll
            for (int t = 0; t < 8; ++t) {
                int s = 2 * i + t - 6;
                if (s < 0) s = -s;
                if (s >= 36) s = 70 - s;
                float xv = (s >= 35) ? 0.0f : lo1[s];
                sl += xv * GL[t]; sh += xv * GH[t];
            }
            lo2[i] = sl;
            WdL[(49 + i) * 64 + j] = sh;
        }
#pragma unroll
        for (int i = 0; i < 14; ++i) {            // level 3: N=21 (+1 zero)
            float sl = 0.f, sh = 0.f;
#pragma unroll
            for (int t = 0; t < 8; ++t) {
                int s = 2 * i + t - 6;
                if (s < 0) s = -s;
                if (s >= 22) s = 42 - s;
                float xv = (s >= 21) ? 0.0f : lo2[s];
                sl += xv * GL[t]; sh += xv * GH[t];
            }
            WdL[i * 64 + j] = sl;
            WdL[(70 + i) * 64 + j] = sh;
        }
    }
    __syncthreads();

    const int sk = blockIdx.x;                    // 0..511 = s*128 + n
    const int s  = sk >> 7;
    const int n  = sk & 127;
    const int hw = tid & 63;
    const int tg = __builtin_amdgcn_readfirstlane((int)(tid >> 6)); // 0..3
    const int t0 = tg * 16;
    const float* wk = cw + (size_t)sk * (84 * 64);
    float acc[16];
#pragma unroll
    for (int j = 0; j < 16; ++j) acc[j] = 0.f;
#pragma unroll 4
    for (int tau = 0; tau < 84; ++tau) {
        float wv = wk[tau * 64 + hw];
        const float* Wr = WdL + tau * 64 + t0;
#pragma unroll
        for (int j = 0; j < 16; ++j) acc[j] += wv * Wr[j];
    }
    // scatter into B-fragment layout
    const int nt = n >> 4;
    const int fr = n & 15;
    const int fq = (hw >> 3) & 3;
    const int jj = hw & 7;
    const int kbh = hw >> 5;                      // kb = t*2 + (hw>>5)
#pragma unroll
    for (int j = 0; j < 16; ++j) {
        const int t = t0 + j;
        const size_t idx =
            ((((size_t)(s * 8 + nt)) * 128 + t * 2 + kbh) * 64 + fq * 16 + fr) * 8 + jj;
        Wf[idx] = f32_bf16(acc[j]);
    }
}

// ---------------------------------------------------------------------------
// Kernel 2: barrier-free, LDS-free MFMA GEMM with K-split.
// wave gw = (ks*4 + s)*128 + mt computes a 16(m) x 128(n) partial tile over
// K-slice [ks*NKB*32, (ks+1)*NKB*32).  A straight from global (fp32->bf16),
// B from pre-swizzled Wf (L2-resident).  P[ks][m][n] partials in workspace.
// ---------------------------------------------------------------------------
template <int NKB>
__global__ __launch_bounds__(256, 3) void gemm2(const float* __restrict__ X,
                                                const u16* __restrict__ Wf,
                                                float* __restrict__ P) {
    const int tid  = threadIdx.x;
    const int lane = tid & 63;
    const int gw   = blockIdx.x * 4 + (tid >> 6);
    const int ksid = gw >> 9;          // K-slice id
    const int rem  = gw & 511;
    const int s    = rem >> 7;         // subwindow 0..3
    const int mt   = rem & 127;        // m-tile (16 rows)
    const int fr   = lane & 15;
    const int fq   = lane >> 4;
    const int kb0  = ksid * NKB;

    const float* xg = X + (size_t)(mt * 16 + fr) * 16384 + s * 4096 + kb0 * 32 + fq * 8;
    const u16*   wg = Wf + (((size_t)(s * 8) * 128) + kb0) * 512 + lane * 8;
    // strides (u16): nt -> 128*512 = 65536 ; kb -> 512

    f32x4 acc[8];
#pragma unroll
    for (int nt = 0; nt < 8; ++nt) acc[nt] = (f32x4){0.f, 0.f, 0.f, 0.f};

    // prefetch A for kb=0
    f32x4 a0 = __builtin_nontemporal_load(reinterpret_cast<const f32x4*>(xg));
    f32x4 a1 = __builtin_nontemporal_load(reinterpret_cast<const f32x4*>(xg) + 1);

#pragma unroll 2
    for (int kb = 0; kb < NKB; ++kb) {
        union { u32 u[4]; bf16x8 v; } av;
        av.u[0] = pack2_bf16(a0.x, a0.y); av.u[1] = pack2_bf16(a0.z, a0.w);
        av.u[2] = pack2_bf16(a1.x, a1.y); av.u[3] = pack2_bf16(a1.z, a1.w);
        // prefetch next A (clamped; redundant reload on last iter is harmless)
        const int kn = (kb + 1 < NKB) ? kb + 1 : kb;
        a0 = __builtin_nontemporal_load(reinterpret_cast<const f32x4*>(xg + (size_t)kn * 32));
        a1 = __builtin_nontemporal_load(reinterpret_cast<const f32x4*>(xg + (size_t)kn * 32) + 1);
        const u16* wb = wg + (size_t)kb * 512;
#pragma unroll
        for (int nt = 0; nt < 8; ++nt) {
            bf16x8 bf = *reinterpret_cast<const bf16x8*>(wb + (size_t)nt * 65536);
            acc[nt] = __builtin_amdgcn_mfma_f32_16x16x32_bf16(av.v, bf, acc[nt], 0, 0, 0);
        }
    }

    // partial write: P[ksid][mt*16 + fq*4 + r][s*128 + nt*16 + fr]
    float* pg = P + (size_t)ksid * (2048 * 512) + (size_t)(mt * 16) * 512 + s * 128 + fr;
#pragma unroll
    for (int nt = 0; nt < 8; ++nt)
#pragma unroll
        for (int r = 0; r < 4; ++r)
            __builtin_nontemporal_store(acc[nt][r], pg + (size_t)(fq * 4 + r) * 512 + nt * 16);
}

// ---------------------------------------------------------------------------
// Kernel 3: reduce K-slices, add bias, leaky-ReLU.
// ---------------------------------------------------------------------------
__global__ __launch_bounds__(256) void reduce_k(const float* __restrict__ P,
                                                const float* __restrict__ bias,
                                                float* __restrict__ out, int nks) {
    const int t = blockIdx.x * 256 + threadIdx.x;     // 0..262143
    const size_t base = (size_t)t * 4;
    f32x4 sum = {0.f, 0.f, 0.f, 0.f};
    for (int k = 0; k < nks; ++k) {
        f32x4 v = __builtin_nontemporal_load(
            reinterpret_cast<const f32x4*>(P + (size_t)k * (2048 * 512) + base));
        sum += v;
    }
    const f32x4 b = *reinterpret_cast<const f32x4*>(bias + (base & 511));
    f32x4 o = sum + b;
    o.x = o.x > 0.f ? o.x : 0.01f * o.x;
    o.y = o.y > 0.f ? o.y : 0.01f * o.y;
    o.z = o.z > 0.f ? o.z : 0.01f * o.z;
    o.w = o.w > 0.f ? o.w : 0.01f * o.w;
    __builtin_nontemporal_store(o, reinterpret_cast<f32x4*>(out + base));
}

// ---------------------------------------------------------------------------
extern "C" void kernel_launch(void* const* d_in, const int* in_sizes, int n_in,
                              void* d_out, int out_size, void* d_ws, size_t ws_size,
                              hipStream_t stream) {
    const float* x  = (const float*)d_in[0];   // [2048,1,256,8,8] fp32
    const float* cw = (const float*)d_in[1];   // [4,128,84,8,8]   fp32
    const float* cb = (const float*)d_in[2];   // [4,128]          fp32
    float* out = (float*)d_out;                // [2048,512]       fp32

    u16*   Wf = (u16*)d_ws;                              // 4 MiB, B-fragment order
    float* P  = (float*)((char*)d_ws + (4u << 20));      // KS * 4 MiB partials

    const size_t MN = (size_t)2048 * 512 * 4;            // 4 MiB per K-slice
    int ks = (ws_size >= (4u << 20) + 8 * MN) ? 8
           : (ws_size >= (4u << 20) + 4 * MN) ? 4
           : (ws_size >= (4u << 20) + 2 * MN) ? 2 : 1;

    fold_w<<<512, 256, 0, stream>>>(cw, Wf);
    switch (ks) {
        case 8: gemm2<16> <<<128 * 8, 256, 0, stream>>>(x, Wf, P); break;
        case 4: gemm2<32> <<<128 * 4, 256, 0, stream>>>(x, Wf, P); break;
        case 2: gemm2<64> <<<128 * 2, 256, 0, stream>>>(x, Wf, P); break;
        default: gemm2<128><<<128 * 1, 256, 0, stream>>>(x, Wf, P); break;
    }
    reduce_k<<<1024, 256, 0, stream>>>(P, cb, out, ks);
}